// Round 6
// baseline (825.055 us; speedup 1.0000x reference)
//
#include <hip/hip_runtime.h>

// Batched Jacobi diffusion, B=8, 128x128, iters=1000.
// Round 19: GHOST-ZONE split. Evidence r13-r18: coefficient live set is
// invariantly 64 regs/lane within one block (4 coefs/elem x 16 elem/lane);
// allocator caps arch VGPRs at 64 (attributes can't move it: r14/r15/r18)
// and parks coefs in AGPRs -> ~437cy/SIMD/step of v_accvgpr churn (~34% of
// runtime). Only fewer elements/thread kills it -> 2 blocks/batch. Per-step
// cross-block sync costs ~2000cy (r16), so exchange G=16 ghost rows every
// 16 steps instead (amortized ~125cy/step; owned rows exact for <=16 steps
// since edge garbage propagates 1 row/step).
//   - 16 blocks: blk b = upper rows 0..79 (owns 0-63), blk b+8 = lower rows
//     48..127 (owns 64-127). Pairs share an XCD (round-robin %8) -> same-L2
//     flag handshake.
//   - 5 rows/wave, IN-PLACE update (order {1,2,3,0,4}, 3 old-row temps):
//     live set ~40 coef + 10 state + temps ~ 62 regs -> fits 64 arch wall.
//   - Exchange: senders store 16 boundary rows -> __threadfence (drain own
//     stores; flag-setter is a DIFFERENT wave) -> barrier -> tid0 release
//     flag=epoch -> ghost waves acquire-spin, reload ghosts, refresh halo
//     LDS parity 0 -> barrier. Parity-slotted buffers make WAR safe.
// ws: [0,32768) bufU[b][p][16][128] up->low; [32768,65536) bufL low->up;
//     ints at +65536: fUp[0..7], fLo[0..7].

#define GH 128
#define GW 128
#define NW 16      // waves per block
#define RPW 5      // rows per wave (80 local rows / 16 waves)
#define NT 1024
#define GSTEP 16   // steps between exchanges = ghost depth

typedef float v2f __attribute__((ext_vector_type(2)));

__device__ __forceinline__ float dpp_shr1(float old_v, float src) {
    // lane l gets lane l-1's src; lane 0 (invalid) keeps old_v (= left clamp)
    return __int_as_float(__builtin_amdgcn_update_dpp(
        __float_as_int(old_v), __float_as_int(src), 0x138, 0xf, 0xf, false));
}
__device__ __forceinline__ float dpp_shl1(float old_v, float src) {
    // lane l gets lane l+1's src; lane 63 (invalid) keeps old_v (= right clamp)
    return __int_as_float(__builtin_amdgcn_update_dpp(
        __float_as_int(old_v), __float_as_int(src), 0x130, 0xf, 0xf, false));
}

// d = a * b.yx   (packed f32 mul; half-swap on src1 via op_sel)
__device__ __forceinline__ v2f pk_mul_yx(v2f a, v2f b) {
    v2f d;
    asm("v_pk_mul_f32 %0, %1, %2 op_sel:[0,1] op_sel_hi:[1,0]"
        : "=v"(d) : "v"(a), "v"(b));
    return d;
}
// d = a * b + c  (packed f32 fma)
__device__ __forceinline__ v2f pk_fma(v2f a, v2f b, v2f c) {
    v2f d;
    asm("v_pk_fma_f32 %0, %1, %2, %3 op_sel:[0,0,0] op_sel_hi:[1,1,1]"
        : "=v"(d) : "v"(a), "v"(b), "v"(c));
    return d;
}

__global__ void zero_flags_kernel(int* __restrict__ flags) {
    if (threadIdx.x < 16) flags[threadIdx.x] = 0;
}

__global__ void __launch_bounds__(NT)
jacobi_flux_kernel(const float* __restrict__ k_all,
                   const int* __restrict__ iters_p,
                   float* __restrict__ out,
                   float* __restrict__ ws)
{
    __shared__ __align__(16) v2f sTop[2][NW][64];   // 16 KB
    __shared__ __align__(16) v2f sBot[2][NW][64];   // 16 KB

    const int blk  = blockIdx.x;
    const int half = blk >> 3;          // 0 = rows 0..79, 1 = rows 48..127
    const int b    = blk & 7;           // batch
    const int tid  = threadIdx.x;
    const int l    = tid & 63;          // lane
    const int w    = tid >> 6;          // wave 0..15
    const int base = half * 48;
    const int R0   = base + w * RPW;    // first grid row of my strip
    const int c0   = l * 2;             // first grid col of my pair
    const float* kb = k_all + b * GH * GW;
    const int iters = *iters_p;

    float* bufU = ws + b * 4096;            // upper->lower, [2][16][128]
    float* bufL = ws + 32768 + b * 4096;    // lower->upper
    int* flags  = (int*)(ws + 65536);
    int* myFlag      = (half == 0) ? (flags + b)     : (flags + 8 + b);
    int* partnerFlag = (half == 0) ? (flags + 8 + b) : (flags + b);

    const int wUp = (w == 0)      ? 0      : w - 1;
    const int wDn = (w == NW - 1) ? NW - 1 : w + 1;
    const bool gTop = (half == 0 && w == 0);        // Dirichlet row 0
    const bool gBot = (half == 1 && w == NW - 1);   // Dirichlet row 127

    // ---- one-time: normalized face conductivities, packed for the
    //      regrouped stencil: rN, rS (vertical), cM=(cE.x,cW.y), cLR=(cW.x,cE.y)
    v2f rN[RPW], rS[RPW], cM[RPW], cLR[RPW];
    #pragma unroll
    for (int i = 0; i < RPW; ++i) {
        const int r  = R0 + i;
        const int ru = (r == 0)      ? 0      : r - 1;
        const int rd = (r == GH - 1) ? GH - 1 : r + 1;
        float v[2][4];
        #pragma unroll
        for (int jj = 0; jj < 2; ++jj) {
            const int c  = c0 + jj;
            const int cl = (c == 0)      ? 0      : c - 1;
            const int cr = (c == GW - 1) ? GW - 1 : c + 1;
            float kc = kb[r * GW + c];
            float kn = 0.5f * (kc + kb[ru * GW + c]);
            float ks = 0.5f * (kc + kb[rd * GW + c]);
            float kw = 0.5f * (kc + kb[r * GW + cl]);
            float ke = 0.5f * (kc + kb[r * GW + cr]);
            float inv = 1.0f / (kn + ks + kw + ke);
            v[jj][0] = kn * inv; v[jj][1] = ks * inv;
            v[jj][2] = kw * inv; v[jj][3] = ke * inv;
        }
        rN[i]  = (v2f){v[0][0], v[1][0]};
        rS[i]  = (v2f){v[0][1], v[1][1]};
        cM[i]  = (v2f){v[0][3], v[1][2]};   // (cE.x, cW.y) pairs with cc.yx
        cLR[i] = (v2f){v[0][2], v[1][3]};   // (cW.x, cE.y) pairs with (lfv,rtv)
    }

    // ---- state (in-place, single array) ----
    v2f A[RPW];
    #pragma unroll
    for (int i = 0; i < RPW; ++i)
        A[i] = (R0 + i == 0) ? (v2f){1.0f, 1.0f} : (v2f){0.0f, 0.0f};

    sTop[0][w][l] = A[0];
    sBot[0][w][l] = A[RPW - 1];
    __syncthreads();

    auto F = [&](int i, v2f up, v2f cc, v2f dn) -> v2f {
        v2f s;
        s.x = dpp_shr1(cc.x, cc.y);   // left  neighbor (clamped at col 0)
        s.y = dpp_shl1(cc.y, cc.x);   // right neighbor (clamped at col 127)
        return pk_fma(rN[i], up,
               pk_fma(rS[i], dn,
               pk_fma(cLR[i], s, pk_mul_yx(cM[i], cc))));
    };

    // in-place step; order {1,2,3,0,4} hides halo LDS latency and needs only
    // 3 old-row temps (each F reads pre-step values exclusively).
    auto stepf = [&](int rp, int wp) {
        v2f hu = sBot[rp][wUp][l];   // grid row R0-1 (old)
        v2f hd = sTop[rp][wDn][l];   // grid row R0+RPW (old)
        v2f o1 = A[1], o2 = A[2], o3 = A[3];
        A[1] = F(1, A[0], o1, o2);   // up = old A0 (untouched yet)
        A[2] = F(2, o1, o2, o3);
        A[3] = F(3, o2, o3, A[4]);   // dn = old A4 (updated last)
        A[0] = F(0, hu, A[0], o1);
        A[4] = F(4, o3, A[4], hd);
        if (gTop) A[0] = (v2f){1.0f, 1.0f};
        if (gBot) A[4] = (v2f){0.0f, 0.0f};
        sTop[wp][w][l] = A[0];
        sBot[wp][w][l] = A[4];
        __syncthreads();
    };

    // bulk ghost exchange at t = multiple of GSTEP (epoch e = t/16, parity e&1)
    auto exchange = [&](int e) {
        const int p = e & 1;
        // 1. senders store owned boundary rows
        #pragma unroll
        for (int i = 0; i < RPW; ++i) {
            const int r = R0 + i;
            if (half == 0) {
                if (r >= 48 && r <= 63)
                    ((v2f*)(bufU + p * 2048 + (r - 48) * 128))[l] = A[i];
            } else {
                if (r >= 64 && r <= 79)
                    ((v2f*)(bufL + p * 2048 + (r - 64) * 128))[l] = A[i];
            }
        }
        __threadfence();        // drain MY stores (flag-setter is another wave)
        __syncthreads();        // all senders drained
        if (tid == 0)
            __hip_atomic_store(myFlag, e, __ATOMIC_RELEASE,
                               __HIP_MEMORY_SCOPE_AGENT);
        // 2. ghost waves pull partner's fresh rows
        const bool reader = (half == 0) ? (R0 + RPW - 1 >= 64) : (R0 <= 63);
        if (reader) {
            while (__hip_atomic_load(partnerFlag, __ATOMIC_ACQUIRE,
                                     __HIP_MEMORY_SCOPE_AGENT) < e) {}
            #pragma unroll
            for (int i = 0; i < RPW; ++i) {
                const int r = R0 + i;
                if (half == 0) {
                    if (r >= 64)
                        A[i] = ((const v2f*)(bufL + p * 2048 + (r - 64) * 128))[l];
                } else {
                    if (r <= 63)
                        A[i] = ((const v2f*)(bufU + p * 2048 + (r - 48) * 128))[l];
                }
            }
            // refresh the halo parity the next step reads (t%16==0 -> rp=0)
            sTop[0][w][l] = A[0];
            sBot[0][w][l] = A[RPW - 1];
        }
        __syncthreads();
    };

    int t = 0;
    while (t + GSTEP <= iters) {
        #pragma unroll
        for (int s = 0; s < GSTEP / 2; ++s) { stepf(0, 1); stepf(1, 0); }
        t += GSTEP;
        if (t < iters) exchange(t >> 4);
    }
    const int rem = iters - t;           // 0..15, ghosts valid (<= GSTEP)
    for (int s = 0; s + 2 <= rem; s += 2) { stepf(0, 1); stepf(1, 0); }
    if (rem & 1) stepf(0, 1);

    // ---- flux at row 64: lower block, wave 3 holds rows 63..67 ----
    if (half == 1 && w == 3) {
        float partial = kb[64 * GW + c0]     * (A[2].x - A[1].x)
                      + kb[64 * GW + c0 + 1] * (A[2].y - A[1].y);
        #pragma unroll
        for (int off = 32; off > 0; off >>= 1)
            partial += __shfl_down(partial, off, 64);
        if (l == 0) out[b] = -partial;
    }
}

extern "C" void kernel_launch(void* const* d_in, const int* in_sizes, int n_in,
                              void* d_out, int out_size, void* d_ws, size_t ws_size,
                              hipStream_t stream)
{
    const float* k     = (const float*)d_in[0];
    const int*   iters = (const int*)d_in[1];
    float*       out   = (float*)d_out;
    int*         flags = (int*)d_ws + 65536;
    zero_flags_kernel<<<dim3(1), dim3(64), 0, stream>>>(flags);
    jacobi_flux_kernel<<<dim3(16), dim3(NT), 0, stream>>>(k, iters, out, (float*)d_ws);
}